// Round 1
// baseline (1300.083 us; speedup 1.0000x reference)
//
#include <hip/hip_runtime.h>

#define NB 8
#define NC 256
#define DF 16384
#define KCL 16
#define TK 16

// ---------------- reduction helper: argmax over 256 threads, first-occurrence ----
__device__ __forceinline__ int argmax256(float v, float* sv, int* si) {
  int t = threadIdx.x;
  sv[t] = v; si[t] = t;
  __syncthreads();
  #pragma unroll
  for (int s = 128; s >= 1; s >>= 1) {
    if (t < s) {
      float a = sv[t], b = sv[t + s];
      int ia = si[t], ib = si[t + s];
      if (b > a || (b == a && ib < ia)) { sv[t] = b; si[t] = ib; }
    }
    __syncthreads();
  }
  int r = si[0];
  __syncthreads();
  return r;
}

// ---------------- K1: Dpos + FPS on pos (1 block, 256 threads) -------------------
__global__ __launch_bounds__(256) void k_pos_fps(const float* __restrict__ pe,
                                                 float* __restrict__ Dpos,
                                                 float* __restrict__ centers0) {
  __shared__ float px[NC], py[NC], pz[NC], pn[NC];
  __shared__ float sv[NC]; __shared__ int si[NC];
  __shared__ int fpsIdx[KCL];
  int t = threadIdx.x;
  float x = pe[t * 3 + 0], y = pe[t * 3 + 1], z = pe[t * 3 + 2];
  px[t] = x; py[t] = y; pz[t] = z;
  float n = x * x + y * y + z * z;
  pn[t] = n;
  __syncthreads();
  float rs = 0.f;
  for (int j = 0; j < NC; ++j) {
    float dot = x * px[j] + y * py[j] + z * pz[j];
    float d2 = n + pn[j] - 2.f * dot;
    float d = sqrtf(fmaxf(d2, 0.f));
    Dpos[t * NC + j] = d;
    rs += d;
  }
  __syncthreads();
  int start = argmax256(rs, sv, si);
  if (t == 0) fpsIdx[0] = start;
  float mind = Dpos[start * NC + t];   // symmetric: row == col
  for (int it = 1; it < KCL; ++it) {
    int far = argmax256(mind, sv, si);
    if (t == 0) fpsIdx[it] = far;
    mind = fminf(mind, Dpos[far * NC + t]);
  }
  __syncthreads();
  if (t < KCL) {
    int p = fpsIdx[t];
    centers0[t * 3 + 0] = px[p];
    centers0[t * 3 + 1] = py[p];
    centers0[t * 3 + 2] = pz[p];
  }
}

// ---------------- K2: batched split-K fp32 GEMM S = ff * ff^T --------------------
// grid (16 tiles, 8 batches, 2 k-chunks), block 256 (16x16, 4x4 microtile)
__global__ __launch_bounds__(256) void k_gemm(const float* __restrict__ ff,
                                              float* __restrict__ spart) {
  int tile = blockIdx.x, b = blockIdx.y, kc = blockIdx.z;
  int ti = tile >> 2, tj = tile & 3;
  const float* A = ff + (size_t)b * NC * DF;
  __shared__ float As[64][TK + 4], Bs[64][TK + 4];  // pad 4: 2-way bank alias (free), float4-aligned
  int tid = threadIdx.x;
  int tx = tid & 15, ty = tid >> 4;
  int lr = tid >> 2, lc = (tid & 3) * 4;
  const float* Abase = A + (size_t)(ti * 64 + lr) * DF + lc + (size_t)kc * (DF / 2);
  const float* Bbase = A + (size_t)(tj * 64 + lr) * DF + lc + (size_t)kc * (DF / 2);
  float acc[4][4] = {};
  for (int kk = 0; kk < DF / 2; kk += TK) {
    float4 av = *(const float4*)(Abase + kk);
    float4 bv = *(const float4*)(Bbase + kk);
    *(float4*)&As[lr][lc] = av;
    *(float4*)&Bs[lr][lc] = bv;
    __syncthreads();
    #pragma unroll
    for (int k = 0; k < TK; ++k) {
      float a[4], bb[4];
      #pragma unroll
      for (int i = 0; i < 4; ++i) a[i] = As[ty * 4 + i][k];
      #pragma unroll
      for (int j = 0; j < 4; ++j) bb[j] = Bs[tx * 4 + j][k];
      #pragma unroll
      for (int i = 0; i < 4; ++i)
        #pragma unroll
        for (int j = 0; j < 4; ++j)
          acc[i][j] = fmaf(a[i], bb[j], acc[i][j]);
    }
    __syncthreads();
  }
  float* outp = spart + (size_t)(kc * NB + b) * NC * NC;
  #pragma unroll
  for (int ii = 0; ii < 4; ++ii) {
    float4 v = make_float4(acc[ii][0], acc[ii][1], acc[ii][2], acc[ii][3]);
    *(float4*)(outp + (size_t)(ti * 64 + ty * 4 + ii) * NC + tj * 64 + tx * 4) = v;
  }
}

// ---------------- K3: D[b][i][j] = sqrt(relu(dii + djj - 2*S)) -------------------
__global__ __launch_bounds__(256) void k_formD(const float* __restrict__ spart,
                                               float* __restrict__ Db) {
  int i = blockIdx.x, b = blockIdx.y, j = threadIdx.x;
  const float* p0 = spart + (size_t)b * NC * NC;
  const float* p1 = spart + (size_t)(NB + b) * NC * NC;
  __shared__ float dg[NC];
  dg[j] = p0[j * NC + j] + p1[j * NC + j];
  __syncthreads();
  float S = p0[i * NC + j] + p1[i * NC + j];
  float d2 = dg[i] + dg[j] - 2.f * S;
  Db[((size_t)b * NC + i) * NC + j] = sqrtf(fmaxf(d2, 0.f));
}

// ---------------- K4: per-batch FPS on Db (8 blocks) -----------------------------
__global__ __launch_bounds__(256) void k_fps_b(const float* __restrict__ Db,
                                               const float* __restrict__ pe,
                                               int* __restrict__ sel,
                                               float* __restrict__ ccoord) {
  int b = blockIdx.x, t = threadIdx.x;
  const float* D = Db + (size_t)b * NC * NC;
  __shared__ float sv[NC]; __shared__ int si[NC];
  __shared__ int fpsIdx[KCL];
  // row sums via column sums (D exactly symmetric by construction) -> coalesced
  float rs = 0.f;
  for (int i = 0; i < NC; ++i) rs += D[i * NC + t];
  int start = argmax256(rs, sv, si);
  if (t == 0) fpsIdx[0] = start;
  float mind = D[start * NC + t];
  for (int it = 1; it < KCL; ++it) {
    int far = argmax256(mind, sv, si);
    if (t == 0) fpsIdx[it] = far;
    mind = fminf(mind, D[far * NC + t]);
  }
  __syncthreads();
  if (t < KCL) {
    int p = fpsIdx[t];
    sel[b * KCL + t] = p;
    ccoord[(b * KCL + t) * 3 + 0] = pe[(b * NC + p) * 3 + 0];
    ccoord[(b * KCL + t) * 3 + 1] = pe[(b * NC + p) * 3 + 1];
    ccoord[(b * KCL + t) * 3 + 2] = pe[(b * NC + p) * 3 + 2];
  }
}

// ---------------- K5: temp_assign + segment means + matching + center update -----
__global__ __launch_bounds__(256) void k_update(const float* __restrict__ pe,
                                                const float* __restrict__ ccoord,
                                                const float* __restrict__ centers0,
                                                float* __restrict__ centers1) {
  __shared__ float cc[NB * KCL * 3];
  __shared__ float cn[NB * KCL];
  __shared__ float sums[KCL][3];
  __shared__ int cnts[KCL];
  __shared__ float avg[KCL][3];
  __shared__ float an[KCL];
  __shared__ float c0[KCL * 3];
  int t = threadIdx.x;
  for (int i = t; i < NB * KCL * 3; i += 256) cc[i] = ccoord[i];
  if (t < KCL * 3) c0[t] = centers0[t];
  if (t < KCL) { sums[t][0] = 0.f; sums[t][1] = 0.f; sums[t][2] = 0.f; cnts[t] = 0; }
  __syncthreads();
  if (t < NB * KCL) {
    float x = cc[t * 3], y = cc[t * 3 + 1], z = cc[t * 3 + 2];
    cn[t] = x * x + y * y + z * z;
  }
  __syncthreads();
  for (int b = 0; b < NB; ++b) {
    int p = b * NC + t;
    float x = pe[p * 3], y = pe[p * 3 + 1], z = pe[p * 3 + 2];
    float n = x * x + y * y + z * z;
    float best = 3.4e38f; int bi = 0;
    #pragma unroll
    for (int k = 0; k < KCL; ++k) {
      int c = b * KCL + k;
      float dot = x * cc[c * 3] + y * cc[c * 3 + 1] + z * cc[c * 3 + 2];
      float d2 = fmaxf(n + cn[c] - 2.f * dot, 0.f);
      if (d2 < best) { best = d2; bi = k; }
    }
    atomicAdd(&sums[bi][0], x);
    atomicAdd(&sums[bi][1], y);
    atomicAdd(&sums[bi][2], z);
    atomicAdd(&cnts[bi], 1);
  }
  __syncthreads();
  if (t < KCL) {
    float c = (float)cnts[t];
    float inv = 1.f / fmaxf(c, 1.f);
    float ax = (cnts[t] > 0) ? sums[t][0] * inv : 0.f;
    float ay = (cnts[t] > 0) ? sums[t][1] * inv : 0.f;
    float az = (cnts[t] > 0) ? sums[t][2] * inv : 0.f;
    avg[t][0] = ax; avg[t][1] = ay; avg[t][2] = az;
    an[t] = ax * ax + ay * ay + az * az;
  }
  __syncthreads();
  if (t < KCL) {
    float x = c0[t * 3], y = c0[t * 3 + 1], z = c0[t * 3 + 2];
    float n = x * x + y * y + z * z;
    float best = 3.4e38f; int bi = 0;
    #pragma unroll
    for (int j = 0; j < KCL; ++j) {
      float dot = x * avg[j][0] + y * avg[j][1] + z * avg[j][2];
      float d2 = fmaxf(n + an[j] - 2.f * dot, 0.f);
      if (d2 < best) { best = d2; bi = j; }
    }
    centers1[t * 3 + 0] = (1.0f - 0.2f) * x + 0.2f * avg[bi][0];
    centers1[t * 3 + 1] = (1.0f - 0.2f) * y + 0.2f * avg[bi][1];
    centers1[t * 3 + 2] = (1.0f - 0.2f) * z + 0.2f * avg[bi][2];
  }
}

// ---------------- K6: stable argsort + greedy capacity assign --------------------
__global__ __launch_bounds__(256) void k_capacity(const float* __restrict__ pe,
                                                  const float* __restrict__ centers1,
                                                  int* __restrict__ outp) {
  __shared__ int order[NC][KCL];
  __shared__ float cx[KCL], cy[KCL], cz[KCL], cn[KCL];
  __shared__ int counts[KCL];
  int t = threadIdx.x;
  if (t < KCL) {
    float x = centers1[t * 3], y = centers1[t * 3 + 1], z = centers1[t * 3 + 2];
    cx[t] = x; cy[t] = y; cz[t] = z;
    cn[t] = x * x + y * y + z * z;
    counts[t] = 0;
  }
  __syncthreads();
  float x = pe[t * 3], y = pe[t * 3 + 1], z = pe[t * 3 + 2];
  float n = x * x + y * y + z * z;
  float v[KCL];
  #pragma unroll
  for (int k = 0; k < KCL; ++k) {
    float dot = x * cx[k] + y * cy[k] + z * cz[k];
    v[k] = fmaxf(n + cn[k] - 2.f * dot, 0.f);  // monotone in sqrt-dist, same ties after clip
  }
  // stable ascending argsort (selection with strict < keeps first index on ties)
  bool used[KCL];
  #pragma unroll
  for (int k = 0; k < KCL; ++k) used[k] = false;
  for (int r = 0; r < KCL; ++r) {
    float best = 3.4e38f; int bi = 0;
    #pragma unroll
    for (int j = 0; j < KCL; ++j) {
      if (!used[j] && v[j] < best) { best = v[j]; bi = j; }
    }
    order[t][r] = bi;
    used[bi] = true;
  }
  __syncthreads();
  if (t == 0) {
    for (int i = 0; i < NC; ++i) {
      int chosen = order[i][0];  // argmax(all-False) -> 0 fallback per reference
      #pragma unroll 1
      for (int r = 0; r < KCL; ++r) {
        int cl = order[i][r];
        if (counts[cl] < 16) { chosen = cl; break; }
      }
      counts[chosen]++;
      outp[i] = chosen;
    }
  }
}

extern "C" void kernel_launch(void* const* d_in, const int* in_sizes, int n_in,
                              void* d_out, int out_size, void* d_ws, size_t ws_size,
                              hipStream_t stream) {
  (void)in_sizes; (void)n_in; (void)out_size; (void)ws_size;
  const float* features = (const float*)d_in[0];
  const float* pe = (const float*)d_in[1];
  char* ws = (char*)d_ws;
  // ws layout (bytes): spart 4 MiB | Db 2 MiB | Dpos 256 KiB | small buffers
  float* spart    = (float*)(ws);                 // 2 * 8 * 256 * 256 fp32
  float* Db       = (float*)(ws + 4194304);       // 8 * 256 * 256 fp32
  float* Dpos     = (float*)(ws + 6291456);       // 256 * 256 fp32
  float* centers0 = (float*)(ws + 6553600);       // 16*3
  float* centers1 = (float*)(ws + 6553792);       // 16*3
  int*   sel      = (int*)  (ws + 6553984);       // 8*16
  float* ccoord   = (float*)(ws + 6554496);       // 8*16*3
  int*   outp     = (int*)d_out;

  hipLaunchKernelGGL(k_pos_fps, dim3(1), dim3(256), 0, stream, pe, Dpos, centers0);
  hipLaunchKernelGGL(k_gemm, dim3(16, 8, 2), dim3(256), 0, stream, features, spart);
  hipLaunchKernelGGL(k_formD, dim3(256, 8), dim3(256), 0, stream, spart, Db);
  hipLaunchKernelGGL(k_fps_b, dim3(8), dim3(256), 0, stream, Db, pe, sel, ccoord);
  hipLaunchKernelGGL(k_update, dim3(1), dim3(256), 0, stream, pe, ccoord, centers0, centers1);
  hipLaunchKernelGGL(k_capacity, dim3(1), dim3(256), 0, stream, pe, centers1, outp);
}

// Round 2
// 444.108 us; speedup vs baseline: 2.9274x; 2.9274x over previous
//
#include <hip/hip_runtime.h>

#define NB 8
#define NC 256
#define DF 16384
#define KCL 16
#define SPLITS 8
#define KC (DF / SPLITS)     // 2048
#define BK 32
#define ITERS (KC / BK)      // 64

typedef _Float16 half8 __attribute__((ext_vector_type(8)));
typedef float floatx4 __attribute__((ext_vector_type(4)));

// ---------------- reduction helper: argmax over 256 threads, first-occurrence ----
__device__ __forceinline__ int argmax256(float v, float* sv, int* si) {
  int t = threadIdx.x;
  sv[t] = v; si[t] = t;
  __syncthreads();
  #pragma unroll
  for (int s = 128; s >= 1; s >>= 1) {
    if (t < s) {
      float a = sv[t], b = sv[t + s];
      int ia = si[t], ib = si[t + s];
      if (b > a || (b == a && ib < ia)) { sv[t] = b; si[t] = ib; }
    }
    __syncthreads();
  }
  int r = si[0];
  __syncthreads();
  return r;
}

// ---------------- K1: Dpos + FPS on pos (1 block, 256 threads) -------------------
__global__ __launch_bounds__(256) void k_pos_fps(const float* __restrict__ pe,
                                                 float* __restrict__ Dpos,
                                                 float* __restrict__ centers0) {
  __shared__ float px[NC], py[NC], pz[NC], pn[NC];
  __shared__ float sv[NC]; __shared__ int si[NC];
  __shared__ int fpsIdx[KCL];
  int t = threadIdx.x;
  float x = pe[t * 3 + 0], y = pe[t * 3 + 1], z = pe[t * 3 + 2];
  px[t] = x; py[t] = y; pz[t] = z;
  float n = x * x + y * y + z * z;
  pn[t] = n;
  __syncthreads();
  float rs = 0.f;
  for (int j = 0; j < NC; ++j) {
    float dot = x * px[j] + y * py[j] + z * pz[j];
    float d2 = n + pn[j] - 2.f * dot;
    float d = sqrtf(fmaxf(d2, 0.f));
    Dpos[t * NC + j] = d;
    rs += d;
  }
  __syncthreads();
  int start = argmax256(rs, sv, si);
  if (t == 0) fpsIdx[0] = start;
  float mind = Dpos[start * NC + t];   // symmetric: row == col
  for (int it = 1; it < KCL; ++it) {
    int far = argmax256(mind, sv, si);
    if (t == 0) fpsIdx[it] = far;
    mind = fminf(mind, Dpos[far * NC + t]);
  }
  __syncthreads();
  if (t < KCL) {
    int p = fpsIdx[t];
    centers0[t * 3 + 0] = px[p];
    centers0[t * 3 + 1] = py[p];
    centers0[t * 3 + 2] = pz[p];
  }
}

// ---------------- K2: MFMA split-f16 Gram. P = Fh*Fh^T + Fh*Fl^T, T = (Fh*Fl^T)^T
// grid (4 tiles, 8 batches, 8 splits) = 256 blocks, 256 threads (4 waves)
__global__ __launch_bounds__(256, 2) void k_gemm_mfma(const float* __restrict__ ff,
                                                      float* __restrict__ Pp,
                                                      float* __restrict__ Tp) {
  __shared__ _Float16 Ah[128][40];   // pad 32->40 halfs (80B rows): frag reads 2-way max
  __shared__ _Float16 Bh[128][40];
  __shared__ _Float16 Bl[128][40];

  const int tid = threadIdx.x;
  const int ti = blockIdx.x >> 1, tj = blockIdx.x & 1;
  const int b = blockIdx.y, sp = blockIdx.z;
  const int wave = tid >> 6, lane = tid & 63;
  const int wr = wave >> 1, wc = wave & 1;
  const int lrow = lane & 15, q = lane >> 4;

  // staging role: thread covers 16 consecutive floats of one row of A and of B
  const int sr = tid >> 1;                 // 0..127
  const int sc = (tid & 1) * 16;           // 0 or 16
  const float* gA = ff + ((size_t)(b * NC + ti * 128 + sr)) * DF + sp * KC + sc;
  const float* gB = ff + ((size_t)(b * NC + tj * 128 + sr)) * DF + sp * KC + sc;

  floatx4 acc1[4][4], acc2[4][4];
  #pragma unroll
  for (int i = 0; i < 4; ++i)
    #pragma unroll
    for (int j = 0; j < 4; ++j) { acc1[i][j] = (floatx4)0.f; acc2[i][j] = (floatx4)0.f; }

  for (int it = 0; it < ITERS; ++it) {
    // global loads first (overlap with previous iter's MFMA tail)
    float4 a0 = *(const float4*)(gA + 0);
    float4 a1 = *(const float4*)(gA + 4);
    float4 a2 = *(const float4*)(gA + 8);
    float4 a3 = *(const float4*)(gA + 12);
    float4 b0 = *(const float4*)(gB + 0);
    float4 b1 = *(const float4*)(gB + 4);
    float4 b2 = *(const float4*)(gB + 8);
    float4 b3 = *(const float4*)(gB + 12);
    gA += BK; gB += BK;

    float fa[16] = {a0.x,a0.y,a0.z,a0.w, a1.x,a1.y,a1.z,a1.w,
                    a2.x,a2.y,a2.z,a2.w, a3.x,a3.y,a3.z,a3.w};
    float fb[16] = {b0.x,b0.y,b0.z,b0.w, b1.x,b1.y,b1.z,b1.w,
                    b2.x,b2.y,b2.z,b2.w, b3.x,b3.y,b3.z,b3.w};
    half8 ah0, ah1, bh0, bh1, bl0, bl1;
    #pragma unroll
    for (int e = 0; e < 8; ++e) {
      ah0[e] = (_Float16)fa[e];
      ah1[e] = (_Float16)fa[e + 8];
      _Float16 h0 = (_Float16)fb[e];
      _Float16 h1 = (_Float16)fb[e + 8];
      bh0[e] = h0; bh1[e] = h1;
      bl0[e] = (_Float16)(fb[e] - (float)h0);
      bl1[e] = (_Float16)(fb[e + 8] - (float)h1);
    }
    __syncthreads();   // previous iter's frag reads done
    *(half8*)&Ah[sr][sc]     = ah0;
    *(half8*)&Ah[sr][sc + 8] = ah1;
    *(half8*)&Bh[sr][sc]     = bh0;
    *(half8*)&Bh[sr][sc + 8] = bh1;
    *(half8*)&Bl[sr][sc]     = bl0;
    *(half8*)&Bl[sr][sc + 8] = bl1;
    __syncthreads();   // tiles visible

    half8 af[4], bhf[4], blf[4];
    #pragma unroll
    for (int i = 0; i < 4; ++i)
      af[i] = *(const half8*)&Ah[wr * 64 + i * 16 + lrow][q * 8];
    #pragma unroll
    for (int j = 0; j < 4; ++j) {
      bhf[j] = *(const half8*)&Bh[wc * 64 + j * 16 + lrow][q * 8];
      blf[j] = *(const half8*)&Bl[wc * 64 + j * 16 + lrow][q * 8];
    }
    #pragma unroll
    for (int i = 0; i < 4; ++i)
      #pragma unroll
      for (int j = 0; j < 4; ++j) {
        acc1[i][j] = __builtin_amdgcn_mfma_f32_16x16x32_f16(af[i], bhf[j], acc1[i][j], 0, 0, 0);
        acc2[i][j] = __builtin_amdgcn_mfma_f32_16x16x32_f16(af[i], blf[j], acc2[i][j], 0, 0, 0);
      }
  }

  // epilogue: P = acc1 + acc2 at (row,col); T = acc2 at (col,row) [float4 over reg-dim]
  float* Pbase = Pp + (size_t)(sp * NB + b) * NC * NC;
  float* Tbase = Tp + (size_t)(sp * NB + b) * NC * NC;
  #pragma unroll
  for (int i = 0; i < 4; ++i) {
    int grow = ti * 128 + wr * 64 + i * 16 + q * 4;   // + reg
    #pragma unroll
    for (int j = 0; j < 4; ++j) {
      int gcol = tj * 128 + wc * 64 + j * 16 + lrow;
      #pragma unroll
      for (int r = 0; r < 4; ++r)
        Pbase[(size_t)(grow + r) * NC + gcol] = acc1[i][j][r] + acc2[i][j][r];
      *(float4*)&Tbase[(size_t)gcol * NC + grow] = *(float4*)&acc2[i][j];
    }
  }
}

// ---------------- K3a: diag of full Gram per batch ------------------------------
__global__ __launch_bounds__(256) void k_diag(const float* __restrict__ Pp,
                                              const float* __restrict__ Tp,
                                              float* __restrict__ dg) {
  int b = blockIdx.x, t = threadIdx.x;
  float s = 0.f;
  for (int sp = 0; sp < SPLITS; ++sp) {
    size_t idx = ((size_t)(sp * NB + b) * NC + t) * NC + t;
    s += Pp[idx] + Tp[idx];
  }
  dg[b * NC + t] = s;
}

// ---------------- K3b: D[b][i][j] = sqrt(relu(dg_i + dg_j - 2*S)) ----------------
__global__ __launch_bounds__(256) void k_formD(const float* __restrict__ Pp,
                                               const float* __restrict__ Tp,
                                               const float* __restrict__ dg,
                                               float* __restrict__ Db) {
  int i = blockIdx.x, b = blockIdx.y, j = threadIdx.x;
  float acc = 0.f;
  #pragma unroll
  for (int sp = 0; sp < SPLITS; ++sp) {
    size_t idx = ((size_t)(sp * NB + b) * NC + i) * NC + j;
    acc += Pp[idx] + Tp[idx];
  }
  float d2 = dg[b * NC + i] + dg[b * NC + j] - 2.f * acc;
  Db[((size_t)b * NC + i) * NC + j] = sqrtf(fmaxf(d2, 0.f));
}

// ---------------- K4: per-batch FPS on Db (8 blocks) -----------------------------
__global__ __launch_bounds__(256) void k_fps_b(const float* __restrict__ Db,
                                               const float* __restrict__ pe,
                                               int* __restrict__ sel,
                                               float* __restrict__ ccoord) {
  int b = blockIdx.x, t = threadIdx.x;
  const float* D = Db + (size_t)b * NC * NC;
  __shared__ float sv[NC]; __shared__ int si[NC];
  __shared__ int fpsIdx[KCL];
  float rs = 0.f;
  for (int i = 0; i < NC; ++i) rs += D[i * NC + t];   // symmetric -> column sums
  int start = argmax256(rs, sv, si);
  if (t == 0) fpsIdx[0] = start;
  float mind = D[start * NC + t];
  for (int it = 1; it < KCL; ++it) {
    int far = argmax256(mind, sv, si);
    if (t == 0) fpsIdx[it] = far;
    mind = fminf(mind, D[far * NC + t]);
  }
  __syncthreads();
  if (t < KCL) {
    int p = fpsIdx[t];
    sel[b * KCL + t] = p;
    ccoord[(b * KCL + t) * 3 + 0] = pe[(b * NC + p) * 3 + 0];
    ccoord[(b * KCL + t) * 3 + 1] = pe[(b * NC + p) * 3 + 1];
    ccoord[(b * KCL + t) * 3 + 2] = pe[(b * NC + p) * 3 + 2];
  }
}

// ---------------- K5: temp_assign + segment means + matching + center update -----
__global__ __launch_bounds__(256) void k_update(const float* __restrict__ pe,
                                                const float* __restrict__ ccoord,
                                                const float* __restrict__ centers0,
                                                float* __restrict__ centers1) {
  __shared__ float cc[NB * KCL * 3];
  __shared__ float cn[NB * KCL];
  __shared__ float sums[KCL][3];
  __shared__ int cnts[KCL];
  __shared__ float avg[KCL][3];
  __shared__ float an[KCL];
  __shared__ float c0[KCL * 3];
  int t = threadIdx.x;
  for (int i = t; i < NB * KCL * 3; i += 256) cc[i] = ccoord[i];
  if (t < KCL * 3) c0[t] = centers0[t];
  if (t < KCL) { sums[t][0] = 0.f; sums[t][1] = 0.f; sums[t][2] = 0.f; cnts[t] = 0; }
  __syncthreads();
  if (t < NB * KCL) {
    float x = cc[t * 3], y = cc[t * 3 + 1], z = cc[t * 3 + 2];
    cn[t] = x * x + y * y + z * z;
  }
  __syncthreads();
  for (int b = 0; b < NB; ++b) {
    int p = b * NC + t;
    float x = pe[p * 3], y = pe[p * 3 + 1], z = pe[p * 3 + 2];
    float n = x * x + y * y + z * z;
    float best = 3.4e38f; int bi = 0;
    #pragma unroll
    for (int k = 0; k < KCL; ++k) {
      int c = b * KCL + k;
      float dot = x * cc[c * 3] + y * cc[c * 3 + 1] + z * cc[c * 3 + 2];
      float d2 = fmaxf(n + cn[c] - 2.f * dot, 0.f);
      if (d2 < best) { best = d2; bi = k; }
    }
    atomicAdd(&sums[bi][0], x);
    atomicAdd(&sums[bi][1], y);
    atomicAdd(&sums[bi][2], z);
    atomicAdd(&cnts[bi], 1);
  }
  __syncthreads();
  if (t < KCL) {
    float c = (float)cnts[t];
    float inv = 1.f / fmaxf(c, 1.f);
    float ax = (cnts[t] > 0) ? sums[t][0] * inv : 0.f;
    float ay = (cnts[t] > 0) ? sums[t][1] * inv : 0.f;
    float az = (cnts[t] > 0) ? sums[t][2] * inv : 0.f;
    avg[t][0] = ax; avg[t][1] = ay; avg[t][2] = az;
    an[t] = ax * ax + ay * ay + az * az;
  }
  __syncthreads();
  if (t < KCL) {
    float x = c0[t * 3], y = c0[t * 3 + 1], z = c0[t * 3 + 2];
    float n = x * x + y * y + z * z;
    float best = 3.4e38f; int bi = 0;
    #pragma unroll
    for (int j = 0; j < KCL; ++j) {
      float dot = x * avg[j][0] + y * avg[j][1] + z * avg[j][2];
      float d2 = fmaxf(n + an[j] - 2.f * dot, 0.f);
      if (d2 < best) { best = d2; bi = j; }
    }
    centers1[t * 3 + 0] = 0.8f * x + 0.2f * avg[bi][0];
    centers1[t * 3 + 1] = 0.8f * y + 0.2f * avg[bi][1];
    centers1[t * 3 + 2] = 0.8f * z + 0.2f * avg[bi][2];
  }
}

// ---------------- K6: stable argsort + greedy capacity assign --------------------
__global__ __launch_bounds__(256) void k_capacity(const float* __restrict__ pe,
                                                  const float* __restrict__ centers1,
                                                  int* __restrict__ outp) {
  __shared__ int order[NC][KCL];
  __shared__ float cx[KCL], cy[KCL], cz[KCL], cn[KCL];
  __shared__ int counts[KCL];
  int t = threadIdx.x;
  if (t < KCL) {
    float x = centers1[t * 3], y = centers1[t * 3 + 1], z = centers1[t * 3 + 2];
    cx[t] = x; cy[t] = y; cz[t] = z;
    cn[t] = x * x + y * y + z * z;
    counts[t] = 0;
  }
  __syncthreads();
  float x = pe[t * 3], y = pe[t * 3 + 1], z = pe[t * 3 + 2];
  float n = x * x + y * y + z * z;
  float v[KCL];
  #pragma unroll
  for (int k = 0; k < KCL; ++k) {
    float dot = x * cx[k] + y * cy[k] + z * cz[k];
    v[k] = fmaxf(n + cn[k] - 2.f * dot, 0.f);
  }
  bool used[KCL];
  #pragma unroll
  for (int k = 0; k < KCL; ++k) used[k] = false;
  for (int r = 0; r < KCL; ++r) {
    float best = 3.4e38f; int bi = 0;
    #pragma unroll
    for (int j = 0; j < KCL; ++j) {
      if (!used[j] && v[j] < best) { best = v[j]; bi = j; }
    }
    order[t][r] = bi;
    used[bi] = true;
  }
  __syncthreads();
  if (t == 0) {
    for (int i = 0; i < NC; ++i) {
      int chosen = order[i][0];
      #pragma unroll 1
      for (int r = 0; r < KCL; ++r) {
        int cl = order[i][r];
        if (counts[cl] < 16) { chosen = cl; break; }
      }
      counts[chosen]++;
      outp[i] = chosen;
    }
  }
}

extern "C" void kernel_launch(void* const* d_in, const int* in_sizes, int n_in,
                              void* d_out, int out_size, void* d_ws, size_t ws_size,
                              hipStream_t stream) {
  (void)in_sizes; (void)n_in; (void)out_size; (void)ws_size;
  const float* features = (const float*)d_in[0];
  const float* pe = (const float*)d_in[1];
  char* ws = (char*)d_ws;
  // ws layout (bytes):
  float* Pp       = (float*)(ws);                  // 8*8*256*256*4 = 16 MiB
  float* Tp       = (float*)(ws + 16777216);       // 16 MiB
  float* Db       = (float*)(ws + 33554432);       // 2 MiB
  float* Dpos     = (float*)(ws + 35651584);       // 256 KiB
  float* dg       = (float*)(ws + 35913728);       // 8 KiB
  float* centers0 = (float*)(ws + 35921920);
  float* centers1 = (float*)(ws + 35922176);
  int*   sel      = (int*)  (ws + 35922432);
  float* ccoord   = (float*)(ws + 35922944);
  int*   outp     = (int*)d_out;

  hipLaunchKernelGGL(k_pos_fps, dim3(1), dim3(256), 0, stream, pe, Dpos, centers0);
  hipLaunchKernelGGL(k_gemm_mfma, dim3(4, NB, SPLITS), dim3(256), 0, stream, features, Pp, Tp);
  hipLaunchKernelGGL(k_diag, dim3(NB), dim3(256), 0, stream, Pp, Tp, dg);
  hipLaunchKernelGGL(k_formD, dim3(NC, NB), dim3(256), 0, stream, Pp, Tp, dg, Db);
  hipLaunchKernelGGL(k_fps_b, dim3(NB), dim3(256), 0, stream, Db, pe, sel, ccoord);
  hipLaunchKernelGGL(k_update, dim3(1), dim3(256), 0, stream, pe, ccoord, centers0, centers1);
  hipLaunchKernelGGL(k_capacity, dim3(1), dim3(256), 0, stream, pe, centers1, outp);
}

// Round 3
// 365.609 us; speedup vs baseline: 3.5559x; 1.2147x over previous
//
#include <hip/hip_runtime.h>

#define NB 8
#define NC 256
#define DF 16384
#define KCL 16
#define SPLITS 8
#define KC (DF / SPLITS)     // 2048
#define BK 32
#define ITERS (KC / BK)      // 64
#define NTILE 10

typedef _Float16 half8 __attribute__((ext_vector_type(8)));
typedef float floatx4 __attribute__((ext_vector_type(4)));

__device__ const int TItab[NTILE] = {0,0,0,0,1,1,1,2,2,3};
__device__ const int TJtab[NTILE] = {0,1,2,3,1,2,3,2,3,3};

// ---------------- reduction helper: argmax over 256 threads, first-occurrence ----
__device__ __forceinline__ int argmax256(float v, float* sv, int* si) {
  int t = threadIdx.x;
  sv[t] = v; si[t] = t;
  __syncthreads();
  #pragma unroll
  for (int s = 128; s >= 1; s >>= 1) {
    if (t < s) {
      float a = sv[t], b = sv[t + s];
      int ia = si[t], ib = si[t + s];
      if (b > a || (b == a && ib < ia)) { sv[t] = b; si[t] = ib; }
    }
    __syncthreads();
  }
  int r = si[0];
  __syncthreads();
  return r;
}

// ---------------- K1: Dpos + FPS on pos (1 block, 256 threads) -------------------
__global__ __launch_bounds__(256) void k_pos_fps(const float* __restrict__ pe,
                                                 float* __restrict__ Dpos,
                                                 float* __restrict__ centers0) {
  __shared__ float px[NC], py[NC], pz[NC], pn[NC];
  __shared__ float sv[NC]; __shared__ int si[NC];
  __shared__ int fpsIdx[KCL];
  int t = threadIdx.x;
  float x = pe[t * 3 + 0], y = pe[t * 3 + 1], z = pe[t * 3 + 2];
  px[t] = x; py[t] = y; pz[t] = z;
  float n = x * x + y * y + z * z;
  pn[t] = n;
  __syncthreads();
  float rs = 0.f;
  for (int j = 0; j < NC; ++j) {
    float dot = x * px[j] + y * py[j] + z * pz[j];
    float d2 = n + pn[j] - 2.f * dot;
    float d = sqrtf(fmaxf(d2, 0.f));
    Dpos[j * NC + t] = d;   // coalesced; valid by symmetry d(t,j)=d(j,t)
    rs += d;
  }
  __syncthreads();
  int start = argmax256(rs, sv, si);
  if (t == 0) fpsIdx[0] = start;
  float mind = Dpos[start * NC + t];
  for (int it = 1; it < KCL; ++it) {
    int far = argmax256(mind, sv, si);
    if (t == 0) fpsIdx[it] = far;
    mind = fminf(mind, Dpos[far * NC + t]);
  }
  __syncthreads();
  if (t < KCL) {
    int p = fpsIdx[t];
    centers0[t * 3 + 0] = px[p];
    centers0[t * 3 + 1] = py[p];
    centers0[t * 3 + 2] = pz[p];
  }
}

// ---------------- K2: MFMA Gram, upper-tri 64x64 tiles, 3 chains -----------------
// Full S tile = Fh*Fh^T + Fh*Fl^T + (Fl*Fh^T) emitted symmetric (direct+mirror)
// grid (10 tile-pairs, 8 batches, 8 splits) = 640 blocks, 256 threads
__global__ __launch_bounds__(256, 3) void k_gemm_mfma(const float* __restrict__ ff,
                                                      float* __restrict__ Pp) {
  __shared__ _Float16 Ah[64][40];   // pad 32->40 halfs: frag reads 2-way max (free)
  __shared__ _Float16 Al[64][40];
  __shared__ _Float16 Bh[64][40];
  __shared__ _Float16 Bl[64][40];

  const int tid = threadIdx.x;
  const int tp = blockIdx.x;
  const int ti = TItab[tp], tj = TJtab[tp];
  const bool diag = (ti == tj);
  const int b = blockIdx.y, sp = blockIdx.z;
  const int wave = tid >> 6, lane = tid & 63;
  const int lrow = lane & 15, q = lane >> 4;

  // staging: thread covers 8 consecutive floats of one row
  const int sr = tid >> 2;            // 0..63
  const int sc = (tid & 3) * 8;       // 0,8,16,24
  const float* gA = ff + ((size_t)(b * NC + ti * 64 + sr)) * DF + sp * KC + sc;
  const float* gB = ff + ((size_t)(b * NC + tj * 64 + sr)) * DF + sp * KC + sc;

  floatx4 a1[4], a2[4], a3[4];
  #pragma unroll
  for (int j = 0; j < 4; ++j) { a1[j] = (floatx4)0.f; a2[j] = (floatx4)0.f; a3[j] = (floatx4)0.f; }

  float4 ra0 = *(const float4*)(gA), ra1 = *(const float4*)(gA + 4);
  float4 rb0 = make_float4(0.f, 0.f, 0.f, 0.f), rb1 = rb0;
  if (!diag) { rb0 = *(const float4*)(gB); rb1 = *(const float4*)(gB + 4); }
  gA += BK; gB += BK;

  for (int it = 0; it < ITERS; ++it) {
    // convert current prefetched regs to hi/lo halves
    float fa[8] = {ra0.x, ra0.y, ra0.z, ra0.w, ra1.x, ra1.y, ra1.z, ra1.w};
    half8 ah, al;
    #pragma unroll
    for (int e = 0; e < 8; ++e) {
      _Float16 h = (_Float16)fa[e];
      ah[e] = h;
      al[e] = (_Float16)(fa[e] - (float)h);
    }
    half8 bh, bl;
    if (!diag) {
      float fb[8] = {rb0.x, rb0.y, rb0.z, rb0.w, rb1.x, rb1.y, rb1.z, rb1.w};
      #pragma unroll
      for (int e = 0; e < 8; ++e) {
        _Float16 h = (_Float16)fb[e];
        bh[e] = h;
        bl[e] = (_Float16)(fb[e] - (float)h);
      }
    }
    __syncthreads();   // previous iter's frag reads complete
    *(half8*)&Ah[sr][sc] = ah;
    *(half8*)&Al[sr][sc] = al;
    if (!diag) {
      *(half8*)&Bh[sr][sc] = bh;
      *(half8*)&Bl[sr][sc] = bl;
    }
    __syncthreads();   // tiles visible
    // prefetch next chunk: in flight under ds_reads + MFMAs (+ other blocks)
    if (it + 1 < ITERS) {
      ra0 = *(const float4*)(gA); ra1 = *(const float4*)(gA + 4);
      if (!diag) { rb0 = *(const float4*)(gB); rb1 = *(const float4*)(gB + 4); }
      gA += BK; gB += BK;
    }
    const _Float16* bhp = diag ? &Ah[0][0] : &Bh[0][0];
    const _Float16* blp = diag ? &Al[0][0] : &Bl[0][0];
    half8 af = *(const half8*)&Ah[wave * 16 + lrow][q * 8];
    half8 lf = *(const half8*)&Al[wave * 16 + lrow][q * 8];
    #pragma unroll
    for (int j = 0; j < 4; ++j) {
      half8 bhf = *(const half8*)(bhp + (j * 16 + lrow) * 40 + q * 8);
      half8 blf = *(const half8*)(blp + (j * 16 + lrow) * 40 + q * 8);
      a1[j] = __builtin_amdgcn_mfma_f32_16x16x32_f16(af, bhf, a1[j], 0, 0, 0);
      a2[j] = __builtin_amdgcn_mfma_f32_16x16x32_f16(af, blf, a2[j], 0, 0, 0);
      a3[j] = __builtin_amdgcn_mfma_f32_16x16x32_f16(lf, bhf, a3[j], 0, 0, 0);
    }
  }

  // epilogue: S[i][j] = a1+a2+a3; C/D layout row=q*4+r, col=lrow
  float* Pb = Pp + (size_t)(sp * NB + b) * NC * NC;
  int grow = ti * 64 + wave * 16 + q * 4;
  #pragma unroll
  for (int j = 0; j < 4; ++j) {
    int gcol = tj * 64 + j * 16 + lrow;
    float4 v;
    v.x = a1[j][0] + a2[j][0] + a3[j][0];
    v.y = a1[j][1] + a2[j][1] + a3[j][1];
    v.z = a1[j][2] + a2[j][2] + a3[j][2];
    v.w = a1[j][3] + a2[j][3] + a3[j][3];
    Pb[(size_t)(grow + 0) * NC + gcol] = v.x;
    Pb[(size_t)(grow + 1) * NC + gcol] = v.y;
    Pb[(size_t)(grow + 2) * NC + gcol] = v.z;
    Pb[(size_t)(grow + 3) * NC + gcol] = v.w;
    if (!diag) *(float4*)&Pb[(size_t)gcol * NC + grow] = v;  // mirror (lower tile)
  }
}

// ---------------- K3a: diag of full Gram per batch ------------------------------
__global__ __launch_bounds__(256) void k_diag(const float* __restrict__ Pp,
                                              float* __restrict__ dg) {
  int b = blockIdx.x, t = threadIdx.x;
  float s = 0.f;
  #pragma unroll
  for (int sp = 0; sp < SPLITS; ++sp)
    s += Pp[((size_t)(sp * NB + b) * NC + t) * NC + t];
  dg[b * NC + t] = s;
}

// ---------------- K3b: D[b][i][j] = sqrt(relu(dg_i + dg_j - 2*S)) ----------------
__global__ __launch_bounds__(256) void k_formD(const float* __restrict__ Pp,
                                               const float* __restrict__ dg,
                                               float* __restrict__ Db) {
  int i = blockIdx.x, b = blockIdx.y, j = threadIdx.x;
  float acc = 0.f;
  #pragma unroll
  for (int sp = 0; sp < SPLITS; ++sp)
    acc += Pp[((size_t)(sp * NB + b) * NC + i) * NC + j];
  float d2 = dg[b * NC + i] + dg[b * NC + j] - 2.f * acc;
  Db[((size_t)b * NC + i) * NC + j] = sqrtf(fmaxf(d2, 0.f));
}

// ---------------- K4: per-batch FPS on Db (8 blocks) -----------------------------
__global__ __launch_bounds__(256) void k_fps_b(const float* __restrict__ Db,
                                               const float* __restrict__ pe,
                                               int* __restrict__ sel,
                                               float* __restrict__ ccoord) {
  int b = blockIdx.x, t = threadIdx.x;
  const float* D = Db + (size_t)b * NC * NC;
  __shared__ float sv[NC]; __shared__ int si[NC];
  __shared__ int fpsIdx[KCL];
  float rs = 0.f;
  for (int i = 0; i < NC; ++i) rs += D[i * NC + t];   // symmetric -> column sums
  int start = argmax256(rs, sv, si);
  if (t == 0) fpsIdx[0] = start;
  float mind = D[start * NC + t];
  for (int it = 1; it < KCL; ++it) {
    int far = argmax256(mind, sv, si);
    if (t == 0) fpsIdx[it] = far;
    mind = fminf(mind, D[far * NC + t]);
  }
  __syncthreads();
  if (t < KCL) {
    int p = fpsIdx[t];
    sel[b * KCL + t] = p;
    ccoord[(b * KCL + t) * 3 + 0] = pe[(b * NC + p) * 3 + 0];
    ccoord[(b * KCL + t) * 3 + 1] = pe[(b * NC + p) * 3 + 1];
    ccoord[(b * KCL + t) * 3 + 2] = pe[(b * NC + p) * 3 + 2];
  }
}

// ---------------- K5: temp_assign + seg-means + matching + update + capacity -----
__global__ __launch_bounds__(256) void k_final(const float* __restrict__ pe,
                                               const float* __restrict__ ccoord,
                                               const float* __restrict__ centers0,
                                               int* __restrict__ outp) {
  __shared__ float cc[NB * KCL * 3];
  __shared__ float cn[NB * KCL];
  __shared__ float sums[KCL][3];
  __shared__ int cnts[KCL];
  __shared__ float avg[KCL][3];
  __shared__ float an[KCL];
  __shared__ float c0[KCL * 3];
  __shared__ float c1x[KCL], c1y[KCL], c1z[KCL], c1n[KCL];
  __shared__ int order[NC][KCL];
  int t = threadIdx.x;
  for (int i = t; i < NB * KCL * 3; i += 256) cc[i] = ccoord[i];
  if (t < KCL * 3) c0[t] = centers0[t];
  if (t < KCL) { sums[t][0] = 0.f; sums[t][1] = 0.f; sums[t][2] = 0.f; cnts[t] = 0; }
  __syncthreads();
  if (t < NB * KCL) {
    float x = cc[t * 3], y = cc[t * 3 + 1], z = cc[t * 3 + 2];
    cn[t] = x * x + y * y + z * z;
  }
  __syncthreads();
  for (int b = 0; b < NB; ++b) {
    int p = b * NC + t;
    float x = pe[p * 3], y = pe[p * 3 + 1], z = pe[p * 3 + 2];
    float n = x * x + y * y + z * z;
    float best = 3.4e38f; int bi = 0;
    #pragma unroll
    for (int k = 0; k < KCL; ++k) {
      int c = b * KCL + k;
      float dot = x * cc[c * 3] + y * cc[c * 3 + 1] + z * cc[c * 3 + 2];
      float d2 = fmaxf(n + cn[c] - 2.f * dot, 0.f);
      if (d2 < best) { best = d2; bi = k; }
    }
    atomicAdd(&sums[bi][0], x);
    atomicAdd(&sums[bi][1], y);
    atomicAdd(&sums[bi][2], z);
    atomicAdd(&cnts[bi], 1);
  }
  __syncthreads();
  if (t < KCL) {
    float c = (float)cnts[t];
    float inv = 1.f / fmaxf(c, 1.f);
    float ax = (cnts[t] > 0) ? sums[t][0] * inv : 0.f;
    float ay = (cnts[t] > 0) ? sums[t][1] * inv : 0.f;
    float az = (cnts[t] > 0) ? sums[t][2] * inv : 0.f;
    avg[t][0] = ax; avg[t][1] = ay; avg[t][2] = az;
    an[t] = ax * ax + ay * ay + az * az;
  }
  __syncthreads();
  if (t < KCL) {
    float x = c0[t * 3], y = c0[t * 3 + 1], z = c0[t * 3 + 2];
    float n = x * x + y * y + z * z;
    float best = 3.4e38f; int bi = 0;
    #pragma unroll
    for (int j = 0; j < KCL; ++j) {
      float dot = x * avg[j][0] + y * avg[j][1] + z * avg[j][2];
      float d2 = fmaxf(n + an[j] - 2.f * dot, 0.f);
      if (d2 < best) { best = d2; bi = j; }
    }
    float nx = 0.8f * x + 0.2f * avg[bi][0];
    float ny = 0.8f * y + 0.2f * avg[bi][1];
    float nz = 0.8f * z + 0.2f * avg[bi][2];
    c1x[t] = nx; c1y[t] = ny; c1z[t] = nz;
    c1n[t] = nx * nx + ny * ny + nz * nz;
  }
  __syncthreads();
  // ---- capacity part: per-thread stable argsort of d2 to the 16 new centers ----
  {
    float x = pe[t * 3], y = pe[t * 3 + 1], z = pe[t * 3 + 2];
    float n = x * x + y * y + z * z;
    float v[KCL];
    #pragma unroll
    for (int k = 0; k < KCL; ++k) {
      float dot = x * c1x[k] + y * c1y[k] + z * c1z[k];
      v[k] = fmaxf(n + c1n[k] - 2.f * dot, 0.f);
    }
    bool used[KCL];
    #pragma unroll
    for (int k = 0; k < KCL; ++k) used[k] = false;
    for (int r = 0; r < KCL; ++r) {
      float best = 3.4e38f; int bi = 0;
      #pragma unroll
      for (int j = 0; j < KCL; ++j) {
        if (!used[j] && v[j] < best) { best = v[j]; bi = j; }
      }
      order[t][r] = bi;
      used[bi] = true;
    }
  }
  __syncthreads();
  // ---- wave-parallel greedy: counts in lane registers, __shfl gather + ballot ----
  if (t < 64) {
    int cnt = 0;                                   // lane r<16 holds count of cluster r
    int cur = (t < KCL) ? order[0][t] : 0;
    for (int i = 0; i < NC; ++i) {
      int nxt = (t < KCL && i + 1 < NC) ? order[i + 1][t] : 0;
      int ccur = __shfl(cnt, cur);                 // count of my candidate cluster
      bool avail = (t < KCL) && (ccur < 16);
      unsigned long long m = __ballot(avail);
      int chosen;
      if (m != 0ull) {
        int rank = __ffsll((unsigned long long)m) - 1;
        chosen = __shfl(cur, rank);
      } else {
        chosen = __shfl(cur, 0);                   // argmax(all-false)=0 fallback
      }
      if (t == chosen) cnt++;
      if (t == 0) outp[i] = chosen;
      cur = nxt;
    }
  }
}

extern "C" void kernel_launch(void* const* d_in, const int* in_sizes, int n_in,
                              void* d_out, int out_size, void* d_ws, size_t ws_size,
                              hipStream_t stream) {
  (void)in_sizes; (void)n_in; (void)out_size; (void)ws_size;
  const float* features = (const float*)d_in[0];
  const float* pe = (const float*)d_in[1];
  char* ws = (char*)d_ws;
  float* Pp       = (float*)(ws);                  // 8*8*256*256*4 = 16 MiB
  float* Db       = (float*)(ws + 16777216);       // 2 MiB
  float* Dpos     = (float*)(ws + 18874368);       // 256 KiB
  float* dg       = (float*)(ws + 19136512);       // 8 KiB
  float* centers0 = (float*)(ws + 19144704);
  int*   sel      = (int*)  (ws + 19145216);
  float* ccoord   = (float*)(ws + 19145728);
  int*   outp     = (int*)d_out;

  hipLaunchKernelGGL(k_pos_fps, dim3(1), dim3(256), 0, stream, pe, Dpos, centers0);
  hipLaunchKernelGGL(k_gemm_mfma, dim3(NTILE, NB, SPLITS), dim3(256), 0, stream, features, Pp);
  hipLaunchKernelGGL(k_diag, dim3(NB), dim3(256), 0, stream, Pp, dg);
  hipLaunchKernelGGL(k_formD, dim3(NC, NB), dim3(256), 0, stream, Pp, dg, Db);
  hipLaunchKernelGGL(k_fps_b, dim3(NB), dim3(256), 0, stream, Db, pe, sel, ccoord);
  hipLaunchKernelGGL(k_final, dim3(1), dim3(256), 0, stream, pe, ccoord, centers0, outp);
}